// Round 17
// baseline (41.345 us; speedup 1.0000x reference)
//
#include <hip/hip_runtime.h>

#define BS  16
#define NN  256
#define HID 128

// 512 blocks: XCD x gets swz in [64x, 64x+64) = batches 2x, 2x+1.
__device__ __forceinline__ int xcd_swz(int bid) {
    return (bid & 7) * 64 + (bid >> 3);
}

// ---------------------------------------------------------------------------
// K1: exact R16 (best measured). 512 blocks, 512 threads, 8 rows/block.
// Split-K quarters; phase 2 fused (ai+aj+g from one hs stream).
// ---------------------------------------------------------------------------
__global__ __launch_bounds__(512, 4) void gat_k1(
    const float* __restrict__ x, const float* __restrict__ W_fc,
    const float* __restrict__ b_fc, const float* __restrict__ W_a1,
    const float* __restrict__ b_a1, const float* __restrict__ W_out,
    float* __restrict__ aiT, float* __restrict__ ajT, float* __restrict__ g)
{
    __shared__ __align__(16) float xs[8][HID];            // 4KB
    __shared__ __align__(16) float hs[8][HID];            // 4KB
    __shared__ __align__(16) float red[4][3][8][HID];     // 48KB

    const int tid = threadIdx.x;
    const int k   = tid & 127;
    const int q   = tid >> 7;                 // 0..3
    const int swz = xcd_swz(blockIdx.x);
    const int r0  = swz * 8;                  // flat row = b*NN + n0
    const int b   = r0 >> 8;
    const int n0  = r0 & 255;

    for (int t = tid; t < 8 * HID; t += 512)
        xs[t >> 7][t & 127] = x[r0 * HID + t];
    __syncthreads();

    // ---- phase 1: h partials, split-K quarter d in [32q, 32q+32) ----
    {
        float acc[8] = {0,0,0,0,0,0,0,0};
        const int dq = 32 * q;
        #pragma unroll 2
        for (int d = 0; d < 32; d += 4) {
            float w[4];
            #pragma unroll
            for (int t = 0; t < 4; ++t) w[t] = W_fc[(dq + d + t) * HID + k];
            #pragma unroll
            for (int r = 0; r < 8; ++r) {
                const float4 xv = *(const float4*)&xs[r][dq + d];
                acc[r] += xv.x * w[0] + xv.y * w[1] + xv.z * w[2] + xv.w * w[3];
            }
        }
        #pragma unroll
        for (int r = 0; r < 8; ++r) red[q][0][r][k] = acc[r];
    }
    __syncthreads();

    // ---- reduce h: thread (k,q) -> rows 2q, 2q+1 ----
    {
        const float bf = b_fc[k];
        #pragma unroll
        for (int r2 = 0; r2 < 2; ++r2) {
            const int r = 2 * q + r2;
            hs[r][k] = (red[0][0][r][k] + red[1][0][r][k])
                     + (red[2][0][r][k] + red[3][0][r][k]) + bf;
        }
    }
    __syncthreads();

    // ---- phase 2 FUSED: ai+aj+g partials over d-quarter, one hs stream ----
    {
        float ai_a[8] = {0,0,0,0,0,0,0,0};
        float aj_a[8] = {0,0,0,0,0,0,0,0};
        float g_a[8]  = {0,0,0,0,0,0,0,0};
        const int dq = 32 * q;
        #pragma unroll 2
        for (int d = 0; d < 32; d += 4) {
            float wi[4], wj[4], wo[4];
            #pragma unroll
            for (int t = 0; t < 4; ++t) {
                wi[t] = W_a1[(dq + d + t) * HID + k];
                wj[t] = W_a1[(HID + dq + d + t) * HID + k];
                wo[t] = W_out[(dq + d + t) * HID + k];
            }
            #pragma unroll
            for (int r = 0; r < 8; ++r) {
                const float4 hv = *(const float4*)&hs[r][dq + d];
                ai_a[r] += hv.x * wi[0] + hv.y * wi[1] + hv.z * wi[2] + hv.w * wi[3];
                aj_a[r] += hv.x * wj[0] + hv.y * wj[1] + hv.z * wj[2] + hv.w * wj[3];
                g_a[r]  += hv.x * wo[0] + hv.y * wo[1] + hv.z * wo[2] + hv.w * wo[3];
            }
        }
        #pragma unroll
        for (int r = 0; r < 8; ++r) {
            red[q][0][r][k] = ai_a[r];
            red[q][1][r][k] = aj_a[r];
            red[q][2][r][k] = g_a[r];
        }
    }
    __syncthreads();

    // ---- reduce + stores ----
    {
        const int is_aj = q >> 1;
        const int rb4   = (q & 1) * 4;
        const float bias = is_aj ? 0.f : b_a1[k];
        float4 v;
        v.x = (red[0][is_aj][rb4 + 0][k] + red[1][is_aj][rb4 + 0][k])
            + (red[2][is_aj][rb4 + 0][k] + red[3][is_aj][rb4 + 0][k]) + bias;
        v.y = (red[0][is_aj][rb4 + 1][k] + red[1][is_aj][rb4 + 1][k])
            + (red[2][is_aj][rb4 + 1][k] + red[3][is_aj][rb4 + 1][k]) + bias;
        v.z = (red[0][is_aj][rb4 + 2][k] + red[1][is_aj][rb4 + 2][k])
            + (red[2][is_aj][rb4 + 2][k] + red[3][is_aj][rb4 + 2][k]) + bias;
        v.w = (red[0][is_aj][rb4 + 3][k] + red[1][is_aj][rb4 + 3][k])
            + (red[2][is_aj][rb4 + 3][k] + red[3][is_aj][rb4 + 3][k]) + bias;
        float* dst = (is_aj ? ajT : aiT) + (b * HID + k) * NN + n0 + rb4;
        *(float4*)dst = v;

        #pragma unroll
        for (int r2 = 0; r2 < 2; ++r2) {
            const int r = 2 * q + r2;
            g[(r0 + r) * HID + k] = (red[0][2][r][k] + red[1][2][r][k])
                                  + (red[2][2][r][k] + red[3][2][r][k]);
        }
    }
}

// ---------------------------------------------------------------------------
// K2: 512 blocks, 512 threads, 8-row i-tile. Phase A: packed {ai,ai,w}
// b128 broadcast (1 ds per k-step, was 2). Phase B: thread owns a k-PAIR,
// wave = (j-quarter, row-half): 4 p-broadcasts feed 32 FMA (64 uniform
// b128/wave, was 128). Softmax 1 row/wave.
// ---------------------------------------------------------------------------
__global__ __launch_bounds__(512, 4) void gat_k2(
    const float* __restrict__ aiT, const float* __restrict__ ajT,
    const float* __restrict__ g,  const int* __restrict__ adj,
    const float* __restrict__ w_a2, const float* __restrict__ b_a2,
    const float* __restrict__ b_out, float* __restrict__ out)
{
    __shared__ __align__(16) float4 aiwp[HID][4];        // 8KB {ai2rp, ai2rp+1, wk, -}
    __shared__ __align__(16) float  buf[2][8][NN];       // 16KB e-halves; later red
    __shared__ __align__(16) float  ep[8][NN];           // 8KB p

    const int tid = threadIdx.x;
    const int swz = xcd_swz(blockIdx.x);
    const int b   = swz >> 5;
    const int i0  = (swz & 31) * 8;
    const int wv  = tid >> 6, lane = tid & 63;

    // stage packed {ai_2rp, ai_2rp+1, w_k}: 512 entries, one per thread
    {
        const int kk = tid >> 2, rp2 = tid & 3;
        const float* ar = aiT + (b * HID + kk) * NN + i0 + 2 * rp2;
        float4 v;
        v.x = ar[0];
        v.y = ar[1];
        v.z = w_a2[kk];
        v.w = 0.f;
        aiwp[kk][rp2] = v;
    }

    // adj prefetch in softmax layout (row wv, cols 4*lane..+3)
    const int4 am = *(const int4*)(adj + (b * NN + i0 + wv) * NN + 4 * lane);
    __syncthreads();

    // ---- phase A: wave (kh, rp): rows 2rp,2rp+1; kk in [64kh,64kh+64);
    //      lane l owns j = 4l..4l+3; ONE b128 broadcast per k-step ----
    const int kh = wv >> 2, rp = wv & 3;
    {
        const float* ajp = ajT + (b * HID + kh * 64) * NN + 4 * lane;
        float4 acc0 = {0,0,0,0}, acc1 = {0,0,0,0}, saw = {0,0,0,0};
        const int kb = kh * 64;
        #pragma unroll 8
        for (int t = 0; t < 64; ++t) {
            const float4 a4 = *(const float4*)(ajp + t * NN);
            const float4 aw = aiwp[kb + t][rp];   // x,y = ai rows; z = wk
            saw.x  = __builtin_fmaf(a4.x, aw.z, saw.x);
            saw.y  = __builtin_fmaf(a4.y, aw.z, saw.y);
            saw.z  = __builtin_fmaf(a4.z, aw.z, saw.z);
            saw.w  = __builtin_fmaf(a4.w, aw.z, saw.w);
            acc0.x = __builtin_fmaf(fmaxf(aw.x, -a4.x), aw.z, acc0.x);
            acc0.y = __builtin_fmaf(fmaxf(aw.x, -a4.y), aw.z, acc0.y);
            acc0.z = __builtin_fmaf(fmaxf(aw.x, -a4.z), aw.z, acc0.z);
            acc0.w = __builtin_fmaf(fmaxf(aw.x, -a4.w), aw.z, acc0.w);
            acc1.x = __builtin_fmaf(fmaxf(aw.y, -a4.x), aw.z, acc1.x);
            acc1.y = __builtin_fmaf(fmaxf(aw.y, -a4.y), aw.z, acc1.y);
            acc1.z = __builtin_fmaf(fmaxf(aw.y, -a4.z), aw.z, acc1.z);
            acc1.w = __builtin_fmaf(fmaxf(aw.y, -a4.w), aw.z, acc1.w);
        }
        const float4 e0 = {acc0.x + saw.x, acc0.y + saw.y,
                           acc0.z + saw.z, acc0.w + saw.w};
        const float4 e1 = {acc1.x + saw.x, acc1.y + saw.y,
                           acc1.z + saw.z, acc1.w + saw.w};
        *(float4*)&buf[kh][2 * rp + 0][4 * lane] = e0;
        *(float4*)&buf[kh][2 * rp + 1][4 * lane] = e1;
    }
    __syncthreads();

    // ---- mask + softmax: wave wv owns row wv ----
    {
        const float ba2 = b_a2[0];
        const float4 u = *(const float4*)&buf[0][wv][4 * lane];
        const float4 v = *(const float4*)&buf[1][wv][4 * lane];
        const float e0 = am.x ? u.x + v.x + ba2 : -1e9f;
        const float e1 = am.y ? u.y + v.y + ba2 : -1e9f;
        const float e2 = am.z ? u.z + v.z + ba2 : -1e9f;
        const float e3 = am.w ? u.w + v.w + ba2 : -1e9f;
        float m = fmaxf(fmaxf(e0, e1), fmaxf(e2, e3));
        #pragma unroll
        for (int off = 32; off; off >>= 1) m = fmaxf(m, __shfl_xor(m, off));
        const float p0 = __expf(e0 - m), p1 = __expf(e1 - m);
        const float p2 = __expf(e2 - m), p3 = __expf(e3 - m);
        float s = (p0 + p1) + (p2 + p3);
        #pragma unroll
        for (int off = 32; off; off >>= 1) s += __shfl_xor(s, off);
        const float inv = 1.f / s;
        const float4 pv = {p0 * inv, p1 * inv, p2 * inv, p3 * inv};
        *(float4*)&ep[wv][4 * lane] = pv;
    }
    __syncthreads();

    // ---- phase B: out = attn @ g. Wave (qh = j-quarter, rh = row-half);
    //      lane owns k-pair 2*lane, 2*lane+1 ----
    float* red = &buf[0][0][0];               // [4][8][HID] = 16KB, aliases buf
    const int qh = wv & 3, rh = wv >> 2;
    {
        float2 o[4];
        #pragma unroll
        for (int r = 0; r < 4; ++r) { o[r].x = 0.f; o[r].y = 0.f; }
        const int jb = qh * 64;
        const float* gb = g + (b * NN + jb) * HID + 2 * lane;
        #pragma unroll 2
        for (int jq = 0; jq < 64; jq += 4) {
            const float2 g0 = *(const float2*)(gb + (jq + 0) * HID);
            const float2 g1 = *(const float2*)(gb + (jq + 1) * HID);
            const float2 g2 = *(const float2*)(gb + (jq + 2) * HID);
            const float2 g3 = *(const float2*)(gb + (jq + 3) * HID);
            #pragma unroll
            for (int r = 0; r < 4; ++r) {
                const float4 pv = *(const float4*)&ep[rh * 4 + r][jb + jq];
                o[r].x += pv.x * g0.x + pv.y * g1.x + pv.z * g2.x + pv.w * g3.x;
                o[r].y += pv.x * g0.y + pv.y * g1.y + pv.z * g2.y + pv.w * g3.y;
            }
        }
        #pragma unroll
        for (int r = 0; r < 4; ++r)
            *(float2*)&red[(qh * 8 + rh * 4 + r) * HID + 2 * lane] = o[r];
    }
    __syncthreads();

    // ---- final reduce: thread (k, qh2) -> rows 2qh2, 2qh2+1 ----
    {
        const int k = tid & 127, qh2 = tid >> 7;
        const float bo = b_out[k];
        #pragma unroll
        for (int r2 = 0; r2 < 2; ++r2) {
            const int r = 2 * qh2 + r2;
            out[(b * NN + i0 + r) * HID + k] =
                (red[(0 + r) * HID + k]  + red[(8 + r) * HID + k]) +
                (red[(16 + r) * HID + k] + red[(24 + r) * HID + k]) + bo;
        }
    }
}

extern "C" void kernel_launch(void* const* d_in, const int* in_sizes, int n_in,
                              void* d_out, int out_size, void* d_ws, size_t ws_size,
                              hipStream_t stream) {
    const float* x     = (const float*)d_in[0];
    const int*   adj   = (const int*)  d_in[1];
    const float* W_fc  = (const float*)d_in[2];
    const float* b_fc  = (const float*)d_in[3];
    const float* W_a1  = (const float*)d_in[4];
    const float* b_a1  = (const float*)d_in[5];
    const float* w_a2  = (const float*)d_in[6];
    const float* b_a2  = (const float*)d_in[7];
    const float* W_out = (const float*)d_in[8];
    const float* b_out = (const float*)d_in[9];
    float* out = (float*)d_out;

    float* ws  = (float*)d_ws;
    float* aiT = ws;                      // aiT[b][k][n]
    float* ajT = ws + BS * NN * HID;      // ajT[b][k][n]
    float* g   = ws + 2 * BS * NN * HID;  // g = h@W_out, [b][n][k]

    gat_k1<<<BS * NN / 8, 512, 0, stream>>>(x, W_fc, b_fc, W_a1, b_a1, W_out,
                                            aiT, ajT, g);
    gat_k2<<<BS * (NN / 8), 512, 0, stream>>>(aiT, ajT, g, adj, w_a2, b_a2,
                                              b_out, out);
}